// Round 7
// baseline (1256.557 us; speedup 1.0000x reference)
//
#include <hip/hip_runtime.h>

// Problem constants: B=8, C=4, H=W=512, K_ITERS=10, ALPHA=2
#define Wd   512
#define W4   128              // float4s per row
#define HWp  262144           // elements per (b,c) plane
#define BC   32               // B*C planes
#define NCH  32               // 16-row chunks per plane
#define F_INF __int_as_float(0x7F800000)

// Agent-coherent (cross-XCD safe, L1-bypassing) scalar accesses
__device__ __forceinline__ float dev_load(const float* p) {
    return __hip_atomic_load(p, __ATOMIC_RELAXED, __HIP_MEMORY_SCOPE_AGENT);
}
__device__ __forceinline__ void dev_store(float* p, float v) {
    __hip_atomic_store(p, v, __ATOMIC_RELAXED, __HIP_MEMORY_SCOPE_AGENT);
}

// ws layout (floats): halo[2][32][32][2][512] (8 MB) | red[960] | total[1] | cnt[320] | done[1]
// red: red[k*96+plane]=min, +32=max, +64=sum   (per-iteration slots, init by init_ws)

__global__ void init_ws(float* __restrict__ red, float* __restrict__ total,
                        unsigned* __restrict__ cnt, unsigned* __restrict__ done)
{
    int i = blockIdx.x * 256 + threadIdx.x;
    if (i < 960) red[i] = ((i % 96) < 32) ? F_INF : 0.0f;
    if (i < 320) cnt[i] = 0u;
    if (i == 0) { *total = 0.0f; *done = 0u; }
}

__global__ __launch_bounds__(256, 4)   // 36.9 KB LDS, VGPR<=128 -> exactly 4 blocks/CU
void hausdorff_persistent(const float* __restrict__ pred,
                          const int*  __restrict__ target,
                          float* __restrict__ out,
                          float* __restrict__ halo,
                          float* __restrict__ red,
                          float* __restrict__ total,
                          unsigned* __restrict__ cnt,
                          unsigned* __restrict__ done)
{
    __shared__ __align__(16) float lds[18][512];   // rows 1..16 own tile, 0/17 halo
    __shared__ float smin[4], smax[4], ssum[4];

    const int bx    = blockIdx.x;      // 0..1023 (plane-major: plane's 32 blocks contiguous)
    const int plane = bx >> 5;
    const int chunk = bx & 31;
    const int t     = threadIdx.x;
    const int col4  = t & 127;
    const int rsub  = t >> 7;          // 0..1
    const int b     = plane >> 2;
    const int c     = plane & 3;

    const float* pp = pred + (size_t)plane * HWp;
    const int*   tp = target + (size_t)b * HWp;

    // prologue: bound = (pred-onehot)^2 into LDS rows 0..17 (incl. plane-edge zeros)
    #pragma unroll
    for (int p = 0; p < 9; ++p) {
        const int lr   = p * 2 + rsub;           // 0..17
        const int grow = chunk * 16 + lr - 1;    // -1..512
        float4 bv = make_float4(0.f, 0.f, 0.f, 0.f);
        if (grow >= 0 && grow < Wd) {
            float4 pv = ((const float4*)pp)[grow * W4 + col4];
            int4   tv = ((const int4*)tp)[grow * W4 + col4];
            float dx = pv.x - (tv.x == c ? 1.0f : 0.0f);
            float dy = pv.y - (tv.y == c ? 1.0f : 0.0f);
            float dz = pv.z - (tv.z == c ? 1.0f : 0.0f);
            float dw = pv.w - (tv.w == c ? 1.0f : 0.0f);
            bv = make_float4(dx*dx, dy*dy, dz*dz, dw*dw);
        }
        ((float4*)&lds[lr][0])[col4] = bv;
    }
    __syncthreads();

    const bool hasL = (col4 > 0);
    const bool hasR = (col4 < W4 - 1);
    float s = 1.0f, o = 0.0f, ptot = 0.0f;

    for (int k = 0; k < 10; ++k) {
        float* hw = halo + ((((size_t)(k & 1) * BC + plane) * NCH + chunk) * 2) * Wd;

        float4 e[8];
        float lmin = F_INF, lmax = 0.0f, lsum = 0.0f;

        #pragma unroll
        for (int p = 0; p < 8; ++p) {
            const int lr   = 1 + p * 2 + rsub;
            const int grow = chunk * 16 + p * 2 + rsub;
            float4 c4 = ((const float4*)&lds[lr][0])[col4];
            float4 u4 = ((const float4*)&lds[lr - 1][0])[col4];
            float4 d4 = ((const float4*)&lds[lr + 1][0])[col4];
            float lft = hasL ? lds[lr][4 * col4 - 1] : 0.0f;
            float rgt = hasR ? lds[lr][4 * col4 + 4] : 0.0f;

            const float vc = (grow > 0 ? 1.0f : 0.0f) + (grow < Wd - 1 ? 1.0f : 0.0f);
            float4 sum, cnt4;
            sum.x = c4.x + c4.y + u4.x + d4.x + lft;  cnt4.x = 2.0f + (hasL ? 1.0f : 0.0f) + vc;
            sum.y = c4.x + c4.y + c4.z + u4.y + d4.y; cnt4.y = 3.0f + vc;
            sum.z = c4.y + c4.z + c4.w + u4.z + d4.z; cnt4.z = 3.0f + vc;
            sum.w = c4.z + c4.w + rgt + u4.w + d4.w;  cnt4.w = 2.0f + (hasR ? 1.0f : 0.0f) + vc;

            float4 ev;
            ev.x = fmaxf(0.2f * (s * sum.x + o * cnt4.x) - 0.5f, 0.0f);
            ev.y = fmaxf(0.2f * (s * sum.y + o * cnt4.y) - 0.5f, 0.0f);
            ev.z = fmaxf(0.2f * (s * sum.z + o * cnt4.z) - 0.5f, 0.0f);
            ev.w = fmaxf(0.2f * (s * sum.w + o * cnt4.w) - 0.5f, 0.0f);
            e[p] = ev;

            if (k < 9) {   // publish boundary rows for chunk neighbors (agent scope)
                if (p == 0 && rsub == 0) {           // tile row 0
                    dev_store(&hw[4*col4+0], ev.x); dev_store(&hw[4*col4+1], ev.y);
                    dev_store(&hw[4*col4+2], ev.z); dev_store(&hw[4*col4+3], ev.w);
                }
                if (p == 7 && rsub == 1) {           // tile row 15
                    dev_store(&hw[Wd+4*col4+0], ev.x); dev_store(&hw[Wd+4*col4+1], ev.y);
                    dev_store(&hw[Wd+4*col4+2], ev.z); dev_store(&hw[Wd+4*col4+3], ev.w);
                }
            }

            lmin = fminf(lmin, fminf(fminf(ev.x, ev.y), fminf(ev.z, ev.w)));
            lmax = fmaxf(lmax, fmaxf(fmaxf(ev.x, ev.y), fmaxf(ev.z, ev.w)));
            lsum += (ev.x + ev.y) + (ev.z + ev.w);
        }

        __syncthreads();   // all reads of old tile done
        #pragma unroll
        for (int p = 0; p < 8; ++p)
            ((float4*)&lds[1 + p * 2 + rsub][0])[col4] = e[p];

        // wave (64) + block (4 waves) reduction
        for (int off = 32; off > 0; off >>= 1) {
            lmin = fminf(lmin, __shfl_down(lmin, off));
            lmax = fmaxf(lmax, __shfl_down(lmax, off));
            lsum += __shfl_down(lsum, off);
        }
        const int wave = t >> 6;
        if ((t & 63) == 0) { smin[wave] = lmin; smax[wave] = lmax; ssum[wave] = lsum; }
        __syncthreads();
        if (t == 0) {
            float bmin = smin[0], bmax = smax[0], bsum = ssum[0];
            for (int i = 1; i < 4; i++) {
                bmin = fminf(bmin, smin[i]);
                bmax = fmaxf(bmax, smax[i]);
                bsum += ssum[i];
            }
            // nonnegative floats: int compare == float compare (device-scope atomics)
            atomicMin((int*)&red[k * 96 + plane],      __float_as_int(bmin));
            atomicMax((int*)&red[k * 96 + 32 + plane], __float_as_int(bmax));
            atomicAdd(&red[k * 96 + 64 + plane], bsum);
        }

        __threadfence();   // all threads: drain halo stores / atomics to coherent point
        __syncthreads();

        // per-plane barrier: 32 blocks, per-(k,plane) counter (no reset -> no ABA)
        if (t == 0) {
            unsigned* pc = &cnt[k * 32 + plane];
            __hip_atomic_fetch_add(pc, 1u, __ATOMIC_ACQ_REL, __HIP_MEMORY_SCOPE_AGENT);
            while (__hip_atomic_load(pc, __ATOMIC_ACQUIRE, __HIP_MEMORY_SCOPE_AGENT) < 32u)
                __builtin_amdgcn_s_sleep(1);
        }
        __syncthreads();

        // per-plane affine for next iteration (coherent reads past L1)
        {
            float mn = dev_load(&red[k * 96 + plane]);
            float mx = dev_load(&red[k * 96 + 32 + plane]);
            float dn = mx - mn;
            if (dn != 0.0f) { s = 1.0f / dn; o = -mn / dn; }
            else            { s = 1.0f;      o = 0.0f; }
        }

        // plane leader accumulates closed-form contribution (same arithmetic as R2/R6)
        if (chunk == 0 && t == 0) {
            float sm = dev_load(&red[k * 96 + 64 + plane]);
            float w  = (float)((k + 1) * (k + 1));
            ptot += (s * sm + o * 262144.0f) * w;
        }

        if (k < 9) {   // pull neighbor boundary rows into LDS halo rows 0 / 17
            const float* hr = halo + (((size_t)(k & 1) * BC + plane) * NCH) * 2 * Wd;
            if (rsub == 0) {
                float4 v = make_float4(0.f, 0.f, 0.f, 0.f);
                if (chunk > 0) {
                    const float* src = hr + (size_t)((chunk - 1) * 2 + 1) * Wd + 4 * col4;
                    v.x = dev_load(src + 0); v.y = dev_load(src + 1);
                    v.z = dev_load(src + 2); v.w = dev_load(src + 3);
                }
                ((float4*)&lds[0][0])[col4] = v;
            } else {
                float4 v = make_float4(0.f, 0.f, 0.f, 0.f);
                if (chunk < NCH - 1) {
                    const float* src = hr + (size_t)((chunk + 1) * 2 + 0) * Wd + 4 * col4;
                    v.x = dev_load(src + 0); v.y = dev_load(src + 1);
                    v.z = dev_load(src + 2); v.w = dev_load(src + 3);
                }
                ((float4*)&lds[17][0])[col4] = v;
            }
            __syncthreads();
        }
    }

    // cross-plane total: leaders add, last one writes out
    if (chunk == 0 && t == 0) {
        atomicAdd(total, ptot);
        unsigned d = __hip_atomic_fetch_add(done, 1u, __ATOMIC_ACQ_REL, __HIP_MEMORY_SCOPE_AGENT);
        if (d == 31u)
            out[0] = dev_load(total) * (1.0f / 8388608.0f);
    }
}

extern "C" void kernel_launch(void* const* d_in, const int* in_sizes, int n_in,
                              void* d_out, int out_size, void* d_ws, size_t ws_size,
                              hipStream_t stream)
{
    const float* pred = (const float*)d_in[0];
    const int* target = (const int*)d_in[1];
    float* out = (float*)d_out;

    float*    halo  = (float*)d_ws;                        // 2*32*32*2*512 = 2,097,152 floats
    float*    red   = halo + 2 * BC * NCH * 2 * Wd;        // 960 floats
    float*    total = red + 960;                           // 1 float
    unsigned* cnt   = (unsigned*)(total + 1);              // 320 uints
    unsigned* done  = cnt + 320;                           // 1 uint

    init_ws<<<4, 256, 0, stream>>>(red, total, cnt, done);
    hausdorff_persistent<<<1024, 256, 0, stream>>>(pred, target, out, halo, red,
                                                   total, cnt, done);
}